// Round 5
// baseline (825.688 us; speedup 1.0000x reference)
//
#include <hip/hip_runtime.h>
#include <hip/hip_bf16.h>
#include <hip/hip_fp16.h>

#define NCLS 40

typedef __attribute__((ext_vector_type(8))) _Float16 half8;
typedef __attribute__((ext_vector_type(4))) _Float16 half4h;
typedef __attribute__((ext_vector_type(2))) _Float16 half2h;
union H2U { half2h h; unsigned u; };

// Column-sliced fp16 layout: buffer = 4 slabs of [N][16] halfs. Slab cg holds
// cols [16cg,16cg+16). Round-2 proved slab pinning cuts agg FETCH 88->37 MB;
// round-3 proved bid-based pinning breaks at small grids. This round pins by
// construction: each block reads its XCD id (HW_REG_XCC_ID, measured m09),
// takes cg = xcd&3, and pops 64-node buckets from a per-cg atomic work queue
// (stealing from other queues when its own drains, so correctness never
// depends on the XCD-id distribution).
// Round-4 fix: the queue-pop break path needed a __syncthreads() before
// break — otherwise thread 0 overwrites sBkt for the next phase before all
// waves have read it (barrier divergence -> nondeterministic output).

// ---------------- CSR build: bucketed counting sort ----------------
#define EPB 16384     // edges per level-1 block
#define MAXB1 128     // max level-1 blocks (E <= MAXB1*EPB)
#define MAXNB 104     // max buckets (N <= MAXNB*1024)

// Fused: blocks [0,nB1) do the edge histogram; blocks [nB1,..) do gemm0
// (X fp32 [N,64] @ W0 -> fp16 sliced out). Independent work, complementary pipes.
__global__ __launch_bounds__(256) void hist_and_gemm(
        const int* __restrict__ dst, int E, int nb, int* __restrict__ blockHist, int nB1,
        const float* __restrict__ X, const float* __restrict__ W,
        _Float16* __restrict__ out, int N) {
    __shared__ int cnt[4][MAXNB];
    int t = threadIdx.x;  // 256
    if ((int)blockIdx.x < nB1) {
        for (int i = t; i < 4 * MAXNB; i += 256) cnt[i / MAXNB][i % MAXNB] = 0;
        __syncthreads();
        int bk = t & 3;
        int base = blockIdx.x * EPB;
        int end = min(base + EPB, E);
        for (int i = base + t; i < end; i += 256) atomicAdd(&cnt[bk][dst[i] >> 10], 1);
        __syncthreads();
        for (int i = t; i < nb; i += 256)
            blockHist[blockIdx.x * nb + i] = cnt[0][i] + cnt[1][i] + cnt[2][i] + cnt[3][i];
        return;
    }
    // ---- gemm0 part ----
    int bid = blockIdx.x - nB1;
    int nBlocks = gridDim.x - nB1;
    int lane = t & 63;
    int waveId = (bid * 256 + t) >> 6;
    int nWaves = (nBlocks * 256) >> 6;
    int p = lane & 31;

    H2U wh[32];
#pragma unroll
    for (int j = 0; j < 32; ++j)
        wh[j].h = half2h{(_Float16)W[(2 * j) * 64 + lane], (_Float16)W[(2 * j + 1) * 64 + lane]};

    const float2* Xf = (const float2*)X;
    auto loadX = [&](int row) -> H2U {
        H2U r; r.u = 0;
        if (row < N) {
            float2 f = Xf[(size_t)row * 32 + p];
            r.h = half2h{(_Float16)f.x, (_Float16)f.y};
        }
        return r;
    };
    int cg = lane >> 4, cc = lane & 15;          // sliced store coords
    int row = waveId;
    H2U xp = loadX(row);
    for (; row < N; row += nWaves) {
        H2U nxt = loadX(row + nWaves);
        float y0 = 0.f, y1 = 0.f;
#pragma unroll
        for (int j2 = 0; j2 < 32; j2 += 2) {
            H2U r0, r1;
            r0.u = __builtin_amdgcn_readlane(xp.u, j2);
            r1.u = __builtin_amdgcn_readlane(xp.u, j2 + 1);
            y0 = __builtin_amdgcn_fdot2(r0.h, wh[j2].h, y0, false);
            y1 = __builtin_amdgcn_fdot2(r1.h, wh[j2 + 1].h, y1, false);
        }
        out[((size_t)cg * N + row) * 16 + cc] = (_Float16)(y0 + y1);
        xp = nxt;
    }
}

// also zeroes the 512-byte reduction scratch + agg work queues, writes esrc pad
__global__ void bucket_scan(const int* __restrict__ blockHist, int nB1, int nb,
                            int* __restrict__ blockBase, int* __restrict__ bucketOffs,
                            int* __restrict__ offs, int N, int E, int* __restrict__ red32,
                            int* __restrict__ esrc, int* __restrict__ qctr) {
    __shared__ int h[MAXB1 * MAXNB];
    __shared__ int btot[MAXNB];
    __shared__ int boffs[MAXNB + 1];
    int t = threadIdx.x;  // 128
    if (t < 128) red32[t] = 0;
    if (t < 16) qctr[t] = 0;
    int total = nB1 * nb;
    for (int i = t; i < total; i += 128) h[i] = blockHist[i];
    __syncthreads();
    for (int b = t; b < nb; b += 128) {
        int run = 0;
        for (int i = 0; i < nB1; ++i) { int v = h[i * nb + b]; h[i * nb + b] = run; run += v; }
        btot[b] = run;
    }
    __syncthreads();
    if (t == 0) {
        int run = 0;
        for (int b = 0; b < nb; ++b) { boffs[b] = run; run += btot[b]; }
        boffs[nb] = run;
    }
    __syncthreads();
    for (int b = t; b < nb; b += 128) {
        int bo = boffs[b];
        for (int i = 0; i < nB1; ++i) h[i * nb + b] += bo;
    }
    __syncthreads();
    for (int i = t; i < total; i += 128) blockBase[i] = h[i];
    for (int b = t; b <= nb; b += 128) bucketOffs[b] = boffs[b];
    if (t == 0) { offs[N] = E; }
    if (t < 8) esrc[E + t] = 0;   // pad (pipeline reads up to esrc[E+4])
}

__global__ void bucket_place(const int* __restrict__ src, const int* __restrict__ dst, int E,
                             int nb, const int* __restrict__ blockBase,
                             unsigned* __restrict__ tmp) {
    __shared__ int cur[MAXNB];
    int t = threadIdx.x;  // 256
    for (int i = t; i < nb; i += 256) cur[i] = blockBase[blockIdx.x * nb + i];
    __syncthreads();
    int base = blockIdx.x * EPB;
    int end = min(base + EPB, E);
    for (int i = base + t; i < end; i += 256) {
        int d = dst[i];
        int s = src[i];
        unsigned pack = ((unsigned)(d & 1023) << 17) | (unsigned)s;  // src < 2^17
        int pos = atomicAdd(&cur[d >> 10], 1);
        tmp[pos] = pack;
    }
}

// esrc entry: bits [26:17] = dst mod 1024 (node id within 1024-bucket),
// bits [16:0] = src. 64-node agg buckets nest inside: dl = (pack>>17)&63.
__global__ __launch_bounds__(512) void bucket_finalize(const unsigned* __restrict__ tmp,
                                                       const int* __restrict__ bucketOffs,
                                                       int N, int* __restrict__ offs,
                                                       int* __restrict__ esrc) {
    __shared__ int cnt[1024];
    __shared__ int wsum[8];
    int b = blockIdx.x;
    int t = threadIdx.x;  // 512
    int bstart = bucketOffs[b], bend = bucketOffs[b + 1];
    cnt[t] = 0;
    cnt[t + 512] = 0;
    __syncthreads();
    for (int i = bstart + t; i < bend; i += 512) atomicAdd(&cnt[tmp[i] >> 17], 1);
    __syncthreads();
    int c0 = cnt[2 * t], c1 = cnt[2 * t + 1];
    int s = c0 + c1;
    int lane = t & 63, w = t >> 6;
    int ssc = s;
    for (int off = 1; off < 64; off <<= 1) {
        int v = __shfl_up(ssc, off, 64);
        if (lane >= off) ssc += v;
    }
    if (lane == 63) wsum[w] = ssc;
    __syncthreads();
    int wo = 0;
#pragma unroll
    for (int k = 0; k < 8; ++k)
        if (k < w) wo += wsum[k];
    int excl = (ssc - s) + wo + bstart;
    __syncthreads();
    int node0 = (b << 10) + 2 * t;
    if (node0 < N) offs[node0] = excl;
    if (node0 + 1 < N) offs[node0 + 1] = excl + c0;
    cnt[2 * t] = excl;
    cnt[2 * t + 1] = excl + c0;
    __syncthreads();
    for (int i = bstart + t; i < bend; i += 512) {
        unsigned p = tmp[i];
        int pos = atomicAdd(&cnt[p >> 17], 1);
        esrc[pos] = (int)(p);   // keep full 10-bit local id + src
    }
}

// ------------- dense X(sliced fp16 or fp32)[N,64] @ W[64,FO] ---------------
__global__ __launch_bounds__(256) void gemm_fdot(const void* __restrict__ X, int xHalf,
                                                 const float* __restrict__ W,
                                                 const float* __restrict__ bias,
                                                 void* __restrict__ out, int outHalf,
                                                 int N, int FO) {
    int lane = threadIdx.x & 63;
    int waveId = (blockIdx.x * blockDim.x + threadIdx.x) >> 6;
    int nWaves = (gridDim.x * blockDim.x) >> 6;
    int cl = lane < FO ? lane : 0;
    int p = lane & 31;

    H2U wh[32];
#pragma unroll
    for (int j = 0; j < 32; ++j)
        wh[j].h = half2h{(_Float16)W[(2 * j) * FO + cl], (_Float16)W[(2 * j + 1) * FO + cl]};
    float gb = 0.f;
    if (bias != nullptr && lane < FO) gb = bias[lane];

    const unsigned* Xh = (const unsigned*)X;   // sliced view: uint (cg*N+row)*8 + (p&7)
    const float2* Xf = (const float2*)X;
    float* outF = (float*)out;
    _Float16* outH = (_Float16*)out;
    int scg = p >> 3, su = p & 7;              // sliced read coords (halfs 2p,2p+1)
    int ocg = lane >> 4, occ = lane & 15;      // sliced write coords

    auto loadX = [&](int row) -> H2U {
        H2U r; r.u = 0;
        if (row < N) {
            if (xHalf) r.u = Xh[((size_t)scg * N + row) * 8 + su];
            else {
                float2 f = Xf[(size_t)row * 32 + p];
                r.h = half2h{(_Float16)f.x, (_Float16)f.y};
            }
        }
        return r;
    };

    int row = waveId;
    H2U xp = loadX(row);
    for (; row < N; row += nWaves) {
        H2U nxt = loadX(row + nWaves);
        float y0 = gb, y1 = 0.f;
#pragma unroll
        for (int j2 = 0; j2 < 32; j2 += 2) {
            H2U r0, r1;
            r0.u = __builtin_amdgcn_readlane(xp.u, j2);
            r1.u = __builtin_amdgcn_readlane(xp.u, j2 + 1);
            y0 = __builtin_amdgcn_fdot2(r0.h, wh[j2].h, y0, false);
            y1 = __builtin_amdgcn_fdot2(r1.h, wh[j2 + 1].h, y1, false);
        }
        float y = y0 + y1;
        if (outHalf) {
            outH[((size_t)ocg * N + row) * 16 + occ] = (_Float16)y;
        } else if (lane < FO) {
            outF[(size_t)row * FO + lane] = y;
        }
        xp = nxt;
    }
}

// fdot2-selector accumulate: a_even += v.lo, a_odd += v.hi (exact: x*1.0, fp32 acc)
#define ACC_PAIR(word, ae, ao)                                        \
    do {                                                              \
        H2U _p; _p.u = (word);                                        \
        (ae) = __builtin_amdgcn_fdot2(_p.h, selE.h, (ae), false);     \
        (ao) = __builtin_amdgcn_fdot2(_p.h, selO.h, (ao), false);     \
    } while (0)

// ---- XCD-self-pinned, work-queue, edge-parallel slab aggregation ----------
// Persistent block: cg0 = (real XCD id)&3; pops 64-node buckets from queue
// ctr[cg], stealing from other cgs when drained (correctness independent of
// XCD mapping). LDS fp32 acc[64][17]; 64 slots x 4 lanes (uint2 = 8 B of the
// 32 B slab row); contiguous dst-sorted chunk per slot; register run
// accumulation, LDS-atomic flush at run boundaries; pack prefetch distance 4,
// row prefetch distance 2. MODE 0: relu(acc+bias); MODE 1: plain.
#define QBKT 64
#define QST 17

template <int MODE>
__global__ __launch_bounds__(256) void agg_q_kernel(
        const _Float16* __restrict__ t, const int* __restrict__ offs,
        const int* __restrict__ esrc, const float* __restrict__ bias,
        _Float16* __restrict__ out, int N, int* __restrict__ ctr, int nBkt) {
    __shared__ float acc[QBKT * QST];
    __shared__ int sBkt;
    int tid = threadIdx.x;  // 256
    int xcd;
    asm volatile("s_getreg_b32 %0, hwreg(HW_REG_XCC_ID)" : "=s"(xcd));
    int cg0 = xcd & 3;

    H2U selE, selO;
    selE.h = half2h{(_Float16)1.f, (_Float16)0.f};
    selO.h = half2h{(_Float16)0.f, (_Float16)1.f};

    for (int ph = 0; ph < 4; ++ph) {
        int cg = (cg0 + ph) & 3;
        const uint2* slab = (const uint2*)(t + (size_t)cg * N * 16);
        for (;;) {
            if (tid == 0) sBkt = atomicAdd(&ctr[cg], 1);
            for (int i = tid; i < QBKT * QST; i += 256) acc[i] = 0.f;
            __syncthreads();
            int b = sBkt;
            if (b >= nBkt) {
                // RACE FIX: all threads must finish reading sBkt before any
                // thread (tid 0, next phase) overwrites it. Without this
                // barrier the block's waves diverge across phases -> UB.
                __syncthreads();
                break;
            }
            int g0 = b << 6;
            int g1 = min(g0 + QBKT, N);
            int beg = offs[g0], end = offs[g1];

            int nE = end - beg;
            int chunk = (nE + 63) >> 6;              // 64 slots
            int slot = tid >> 2;
            int c = tid & 3;                         // 4 lanes x uint2
            int e0 = beg + slot * chunk;
            int e1 = min(e0 + chunk, end);

            if (e0 < e1) {
                float a0 = 0.f, a1 = 0.f, a2 = 0.f, a3 = 0.f;
                int p0 = esrc[e0];
                int p1 = esrc[e0 + 1];
                int p2 = esrc[e0 + 2];
                int p3 = esrc[e0 + 3];
                uint2 v0 = slab[(size_t)(p0 & 0x1FFFF) * 4 + c];
                uint2 v1 = slab[(size_t)(p1 & 0x1FFFF) * 4 + c];
                int cur = (p0 >> 17) & 63;
                for (int e = e0; e < e1; ++e) {
                    uint2 v2 = slab[(size_t)(p2 & 0x1FFFF) * 4 + c];   // row e+2
                    int p4 = esrc[e + 4];                              // pack e+4
                    int dl = (p0 >> 17) & 63;
                    if (dl != cur) {                 // run boundary: flush
                        float* fp = &acc[cur * QST + c * 4];
                        atomicAdd(&fp[0], a0); atomicAdd(&fp[1], a1);
                        atomicAdd(&fp[2], a2); atomicAdd(&fp[3], a3);
                        a0 = a1 = a2 = a3 = 0.f;
                        cur = dl;
                    }
                    ACC_PAIR(v0.x, a0, a1);
                    ACC_PAIR(v0.y, a2, a3);
                    p0 = p1; p1 = p2; p2 = p3; p3 = p4;
                    v0 = v1; v1 = v2;
                }
                float* fp = &acc[cur * QST + c * 4];
                atomicAdd(&fp[0], a0); atomicAdd(&fp[1], a1);
                atomicAdd(&fp[2], a2); atomicAdd(&fp[3], a3);
            }
            __syncthreads();

            // epilogue: 256 threads = 64 nodes x 4 col-quads; 8 B stores
            {
                int node = tid >> 2, cq = tid & 3;
                int gn = g0 + node;
                if (gn < N) {
                    const float* ap = &acc[node * QST + cq * 4];
                    half4h hv;
#pragma unroll
                    for (int k = 0; k < 4; ++k) {
                        float v = ap[k];
                        if (MODE == 0) v = fmaxf(v + bias[cg * 16 + cq * 4 + k], 0.f);
                        hv[k] = (_Float16)v;
                    }
                    *(half4h*)(out + ((size_t)cg * N + gn) * 16 + cq * 4) = hv;
                }
            }
            __syncthreads();   // protect acc + sBkt before next iteration
        }
    }
}

// ---------------- loss ----------------
__global__ void loss_pass(const float* __restrict__ rep, const int* __restrict__ labels, int N,
                          double* __restrict__ colSum, double* __restrict__ pickedSum,
                          int* __restrict__ cnt) {
    const int G = 8;
    const int ROWS = 512;
    int t = threadIdx.x;  // blockDim = 320
    int c = t % NCLS;
    int g = t / NCLS;
    int base = blockIdx.x * ROWS;
    int lim = min(base + ROWS, N);
    double sumLoc = 0.0, pickLoc = 0.0;
    int cntLoc = 0;
    for (int r = base + g; r < lim; r += G) {
        float v = rep[(size_t)r * NCLS + c];
        sumLoc += exp((double)v);
        if (labels[r] == c) { pickLoc += (double)v; cntLoc++; }
    }
    __shared__ double colP[G][NCLS];
    __shared__ int cntP[G][NCLS];
    __shared__ double waveP[5];
    colP[g][c] = sumLoc;
    cntP[g][c] = cntLoc;
    __syncthreads();
    if (g == 0) {
        double tot = 0.0;
        int ctot = 0;
        for (int gg = 0; gg < G; ++gg) { tot += colP[gg][c]; ctot += cntP[gg][c]; }
        atomicAdd(&colSum[c], tot);
        if (ctot) atomicAdd(&cnt[c], ctot);
    }
    double wv = pickLoc;
    for (int off = 32; off; off >>= 1) wv += __shfl_down(wv, off, 64);
    if ((t & 63) == 0) waveP[t >> 6] = wv;
    __syncthreads();
    if (t == 0) {
        double s = 0.0;
        for (int i = 0; i < 5; ++i) s += waveP[i];
        atomicAdd(pickedSum, s);
    }
}

__global__ void finalize_kernel(const double* __restrict__ colSum, const int* __restrict__ cnt,
                                const double* __restrict__ pickedSum, int N,
                                float* __restrict__ lossOut) {
    int t = threadIdx.x;
    double term = 0.0;
    if (t < NCLS) term = (double)cnt[t] * log(colSum[t]);
    for (int off = 32; off; off >>= 1) term += __shfl_down(term, off, 64);
    if (t == 0) lossOut[0] = (float)((term - pickedSum[0]) / (double)N);
}

extern "C" void kernel_launch(void* const* d_in, const int* in_sizes, int n_in,
                              void* d_out, int out_size, void* d_ws, size_t ws_size,
                              hipStream_t stream) {
    const float* features = (const float*)d_in[0];
    const float* W0 = (const float*)d_in[1];
    const float* b0 = (const float*)d_in[2];
    const float* W1 = (const float*)d_in[3];
    const float* b1 = (const float*)d_in[4];
    const float* W2 = (const float*)d_in[5];
    const float* b2 = (const float*)d_in[6];
    const int* src = (const int*)d_in[7];
    const int* dst = (const int*)d_in[8];
    const int* labels = (const int*)d_in[9];

    const int N = in_sizes[0] / 64;
    const int E = in_sizes[7];
    const int NC = in_sizes[6];  // 40

    char* ws = (char*)d_ws;
    size_t off = 0;
    auto alloc = [&](size_t bytes) -> void* {
        void* p = ws + off;
        off = (off + bytes + 255) & ~(size_t)255;
        return p;
    };
    int* offs      = (int*)alloc((size_t)(N + 1) * 4);
    int* esrc      = (int*)alloc((size_t)(E + 8) * 4);  // +8: pipeline pad
    _Float16* bufA = (_Float16*)alloc((size_t)N * 64 * 2);  // sliced [4][N][16]
    _Float16* bufB = (_Float16*)alloc((size_t)N * 64 * 2);  // sliced [4][N][16]
    unsigned* tmp  = (unsigned*)alloc((size_t)E * 4);
    int* blockHist = (int*)alloc((size_t)MAXB1 * MAXNB * 4);
    int* blockBase = (int*)alloc((size_t)MAXB1 * MAXNB * 4);
    int* bucketOffs= (int*)alloc((size_t)(MAXNB + 1) * 4);
    int* qctr      = (int*)alloc(64);                    // 3 aggs x 4 cg queues
    char* red      = (char*)alloc(512);
    double* colSum    = (double*)red;
    double* pickedSum = (double*)(red + 320);
    int* cntRed       = (int*)(red + 328);

    float* rep = (float*)d_out;
    float* lossOut = rep + (size_t)N * NC;

    const int nb  = (N + 1023) >> 10;
    const int nB1 = (E + EPB - 1) / EPB;

    // fused: edge histogram + gemm0 (t0 = fp16(X@W0), sliced) in one dispatch
    hist_and_gemm<<<nB1 + 2048, 256, 0, stream>>>(dst, E, nb, blockHist, nB1,
                                                  features, W0, bufA, N);
    bucket_scan<<<1, 128, 0, stream>>>(blockHist, nB1, nb, blockBase, bucketOffs, offs, N, E,
                                       (int*)red, esrc, qctr);
    bucket_place<<<nB1, 256, 0, stream>>>(src, dst, E, nb, blockBase, tmp);
    bucket_finalize<<<nb, 512, 0, stream>>>(tmp, bucketOffs, N, offs, esrc);

    const int nBkt = (N + QBKT - 1) >> 6;
    const int AGG_GRID = 2048;   // 8 blocks/CU -> 32 waves/CU co-resident

    // layer 0: h1 = fp16(relu(S@t0 + b0))   [sliced]
    agg_q_kernel<0><<<AGG_GRID, 256, 0, stream>>>(bufA, offs, esrc, b0, bufB, N, qctr + 0, nBkt);
    // layer 1: t1 = fp16(h1@W1) ; h2 = fp16(relu(S@t1 + b1))   [sliced]
    gemm_fdot<<<2048, 256, 0, stream>>>(bufB, 1, W1, nullptr, bufA, 1, N, 64);
    agg_q_kernel<0><<<AGG_GRID, 256, 0, stream>>>(bufA, offs, esrc, b1, bufB, N, qctr + 4, nBkt);
    // layer 2 (agg-first): g2 = fp16(S@h2) [sliced] ; rep = g2@W2 + b2 [fp32]
    agg_q_kernel<1><<<AGG_GRID, 256, 0, stream>>>(bufB, offs, esrc, nullptr, bufA, N, qctr + 8, nBkt);
    gemm_fdot<<<2048, 256, 0, stream>>>(bufA, 1, W2, b2, rep, 0, N, NC);

    // loss
    loss_pass<<<(N + 511) / 512, 320, 0, stream>>>(rep, labels, N, colSum, pickedSum, cntRed);
    finalize_kernel<<<1, 64, 0, stream>>>(colSum, cntRed, pickedSum, N, lossOut);
}

// Round 6
// 482.918 us; speedup vs baseline: 1.7098x; 1.7098x over previous
//
#include <hip/hip_runtime.h>
#include <hip/hip_bf16.h>
#include <hip/hip_fp16.h>

#define NCLS 40

typedef __attribute__((ext_vector_type(8))) _Float16 half8;
typedef __attribute__((ext_vector_type(4))) _Float16 half4h;
typedef __attribute__((ext_vector_type(2))) _Float16 half2h;
union H2U { half2h h; unsigned u; };

// Column-sliced fp16 layout: buffer = 4 slabs of [N][16] halfs. Slab cg holds
// cols [16cg,16cg+16). Per-XCD working set = 3.2 MB < 4 MB private L2.
// Pinning history: round-2 (many short blocks, bid&3) -> FETCH 37 MB (works);
// round-3 (multi-generation long blocks) -> 121 MB (reassignment drift);
// round-5 (atomic work queue) -> 192 us (one-cache-line atomic serialization).
// This round: SINGLE-GENERATION static pinning. Grid = 2048 co-resident
// blocks (8/CU); each block grid-strides over 64-node buckets internally, so
// the t=0 bid%8->XCD round-robin assignment can never drift. cg = bid&3,
// rank = bid>>2, stride = grid/4. Zero atomics, zero queue.

// ---------------- CSR build: bucketed counting sort ----------------
#define EPB 16384     // edges per level-1 block
#define MAXB1 128     // max level-1 blocks (E <= MAXB1*EPB)
#define MAXNB 104     // max buckets (N <= MAXNB*1024)

// Fused: blocks [0,nB1) do the edge histogram; blocks [nB1,..) do gemm0
// (X fp32 [N,64] @ W0 -> fp16 sliced out). Independent work, complementary pipes.
__global__ __launch_bounds__(256) void hist_and_gemm(
        const int* __restrict__ dst, int E, int nb, int* __restrict__ blockHist, int nB1,
        const float* __restrict__ X, const float* __restrict__ W,
        _Float16* __restrict__ out, int N) {
    __shared__ int cnt[4][MAXNB];
    int t = threadIdx.x;  // 256
    if ((int)blockIdx.x < nB1) {
        for (int i = t; i < 4 * MAXNB; i += 256) cnt[i / MAXNB][i % MAXNB] = 0;
        __syncthreads();
        int bk = t & 3;
        int base = blockIdx.x * EPB;
        int end = min(base + EPB, E);
        for (int i = base + t; i < end; i += 256) atomicAdd(&cnt[bk][dst[i] >> 10], 1);
        __syncthreads();
        for (int i = t; i < nb; i += 256)
            blockHist[blockIdx.x * nb + i] = cnt[0][i] + cnt[1][i] + cnt[2][i] + cnt[3][i];
        return;
    }
    // ---- gemm0 part ----
    int bid = blockIdx.x - nB1;
    int nBlocks = gridDim.x - nB1;
    int lane = t & 63;
    int waveId = (bid * 256 + t) >> 6;
    int nWaves = (nBlocks * 256) >> 6;
    int p = lane & 31;

    H2U wh[32];
#pragma unroll
    for (int j = 0; j < 32; ++j)
        wh[j].h = half2h{(_Float16)W[(2 * j) * 64 + lane], (_Float16)W[(2 * j + 1) * 64 + lane]};

    const float2* Xf = (const float2*)X;
    auto loadX = [&](int row) -> H2U {
        H2U r; r.u = 0;
        if (row < N) {
            float2 f = Xf[(size_t)row * 32 + p];
            r.h = half2h{(_Float16)f.x, (_Float16)f.y};
        }
        return r;
    };
    int cg = lane >> 4, cc = lane & 15;          // sliced store coords
    int row = waveId;
    H2U xp = loadX(row);
    for (; row < N; row += nWaves) {
        H2U nxt = loadX(row + nWaves);
        float y0 = 0.f, y1 = 0.f;
#pragma unroll
        for (int j2 = 0; j2 < 32; j2 += 2) {
            H2U r0, r1;
            r0.u = __builtin_amdgcn_readlane(xp.u, j2);
            r1.u = __builtin_amdgcn_readlane(xp.u, j2 + 1);
            y0 = __builtin_amdgcn_fdot2(r0.h, wh[j2].h, y0, false);
            y1 = __builtin_amdgcn_fdot2(r1.h, wh[j2 + 1].h, y1, false);
        }
        out[((size_t)cg * N + row) * 16 + cc] = (_Float16)(y0 + y1);
        xp = nxt;
    }
}

// also zeroes the 512-byte reduction scratch, writes the esrc prefetch pad
__global__ void bucket_scan(const int* __restrict__ blockHist, int nB1, int nb,
                            int* __restrict__ blockBase, int* __restrict__ bucketOffs,
                            int* __restrict__ offs, int N, int E, int* __restrict__ red32,
                            int* __restrict__ esrc) {
    __shared__ int h[MAXB1 * MAXNB];
    __shared__ int btot[MAXNB];
    __shared__ int boffs[MAXNB + 1];
    int t = threadIdx.x;  // 128
    if (t < 128) red32[t] = 0;
    int total = nB1 * nb;
    for (int i = t; i < total; i += 128) h[i] = blockHist[i];
    __syncthreads();
    for (int b = t; b < nb; b += 128) {
        int run = 0;
        for (int i = 0; i < nB1; ++i) { int v = h[i * nb + b]; h[i * nb + b] = run; run += v; }
        btot[b] = run;
    }
    __syncthreads();
    if (t == 0) {
        int run = 0;
        for (int b = 0; b < nb; ++b) { boffs[b] = run; run += btot[b]; }
        boffs[nb] = run;
    }
    __syncthreads();
    for (int b = t; b < nb; b += 128) {
        int bo = boffs[b];
        for (int i = 0; i < nB1; ++i) h[i * nb + b] += bo;
    }
    __syncthreads();
    for (int i = t; i < total; i += 128) blockBase[i] = h[i];
    for (int b = t; b <= nb; b += 128) bucketOffs[b] = boffs[b];
    if (t == 0) { offs[N] = E; }
    if (t < 8) esrc[E + t] = 0;   // pad (pipeline reads up to esrc[E+4])
}

__global__ void bucket_place(const int* __restrict__ src, const int* __restrict__ dst, int E,
                             int nb, const int* __restrict__ blockBase,
                             unsigned* __restrict__ tmp) {
    __shared__ int cur[MAXNB];
    int t = threadIdx.x;  // 256
    for (int i = t; i < nb; i += 256) cur[i] = blockBase[blockIdx.x * nb + i];
    __syncthreads();
    int base = blockIdx.x * EPB;
    int end = min(base + EPB, E);
    for (int i = base + t; i < end; i += 256) {
        int d = dst[i];
        int s = src[i];
        unsigned pack = ((unsigned)(d & 1023) << 17) | (unsigned)s;  // src < 2^17
        int pos = atomicAdd(&cur[d >> 10], 1);
        tmp[pos] = pack;
    }
}

// esrc entry: bits [26:17] = dst mod 1024 (node id within 1024-bucket),
// bits [16:0] = src. 64-node agg buckets nest inside: dl = (pack>>17)&63.
__global__ __launch_bounds__(512) void bucket_finalize(const unsigned* __restrict__ tmp,
                                                       const int* __restrict__ bucketOffs,
                                                       int N, int* __restrict__ offs,
                                                       int* __restrict__ esrc) {
    __shared__ int cnt[1024];
    __shared__ int wsum[8];
    int b = blockIdx.x;
    int t = threadIdx.x;  // 512
    int bstart = bucketOffs[b], bend = bucketOffs[b + 1];
    cnt[t] = 0;
    cnt[t + 512] = 0;
    __syncthreads();
    for (int i = bstart + t; i < bend; i += 512) atomicAdd(&cnt[tmp[i] >> 17], 1);
    __syncthreads();
    int c0 = cnt[2 * t], c1 = cnt[2 * t + 1];
    int s = c0 + c1;
    int lane = t & 63, w = t >> 6;
    int ssc = s;
    for (int off = 1; off < 64; off <<= 1) {
        int v = __shfl_up(ssc, off, 64);
        if (lane >= off) ssc += v;
    }
    if (lane == 63) wsum[w] = ssc;
    __syncthreads();
    int wo = 0;
#pragma unroll
    for (int k = 0; k < 8; ++k)
        if (k < w) wo += wsum[k];
    int excl = (ssc - s) + wo + bstart;
    __syncthreads();
    int node0 = (b << 10) + 2 * t;
    if (node0 < N) offs[node0] = excl;
    if (node0 + 1 < N) offs[node0 + 1] = excl + c0;
    cnt[2 * t] = excl;
    cnt[2 * t + 1] = excl + c0;
    __syncthreads();
    for (int i = bstart + t; i < bend; i += 512) {
        unsigned p = tmp[i];
        int pos = atomicAdd(&cnt[p >> 17], 1);
        esrc[pos] = (int)(p);   // keep full 10-bit local id + src
    }
}

// ------------- dense X(sliced fp16 or fp32)[N,64] @ W[64,FO] ---------------
__global__ __launch_bounds__(256) void gemm_fdot(const void* __restrict__ X, int xHalf,
                                                 const float* __restrict__ W,
                                                 const float* __restrict__ bias,
                                                 void* __restrict__ out, int outHalf,
                                                 int N, int FO) {
    int lane = threadIdx.x & 63;
    int waveId = (blockIdx.x * blockDim.x + threadIdx.x) >> 6;
    int nWaves = (gridDim.x * blockDim.x) >> 6;
    int cl = lane < FO ? lane : 0;
    int p = lane & 31;

    H2U wh[32];
#pragma unroll
    for (int j = 0; j < 32; ++j)
        wh[j].h = half2h{(_Float16)W[(2 * j) * FO + cl], (_Float16)W[(2 * j + 1) * FO + cl]};
    float gb = 0.f;
    if (bias != nullptr && lane < FO) gb = bias[lane];

    const unsigned* Xh = (const unsigned*)X;   // sliced view: uint (cg*N+row)*8 + (p&7)
    const float2* Xf = (const float2*)X;
    float* outF = (float*)out;
    _Float16* outH = (_Float16*)out;
    int scg = p >> 3, su = p & 7;              // sliced read coords (halfs 2p,2p+1)
    int ocg = lane >> 4, occ = lane & 15;      // sliced write coords

    auto loadX = [&](int row) -> H2U {
        H2U r; r.u = 0;
        if (row < N) {
            if (xHalf) r.u = Xh[((size_t)scg * N + row) * 8 + su];
            else {
                float2 f = Xf[(size_t)row * 32 + p];
                r.h = half2h{(_Float16)f.x, (_Float16)f.y};
            }
        }
        return r;
    };

    int row = waveId;
    H2U xp = loadX(row);
    for (; row < N; row += nWaves) {
        H2U nxt = loadX(row + nWaves);
        float y0 = gb, y1 = 0.f;
#pragma unroll
        for (int j2 = 0; j2 < 32; j2 += 2) {
            H2U r0, r1;
            r0.u = __builtin_amdgcn_readlane(xp.u, j2);
            r1.u = __builtin_amdgcn_readlane(xp.u, j2 + 1);
            y0 = __builtin_amdgcn_fdot2(r0.h, wh[j2].h, y0, false);
            y1 = __builtin_amdgcn_fdot2(r1.h, wh[j2 + 1].h, y1, false);
        }
        float y = y0 + y1;
        if (outHalf) {
            outH[((size_t)ocg * N + row) * 16 + occ] = (_Float16)y;
        } else if (lane < FO) {
            outF[(size_t)row * FO + lane] = y;
        }
        xp = nxt;
    }
}

// fdot2-selector accumulate: a_even += v.lo, a_odd += v.hi (exact: x*1.0, fp32 acc)
#define ACC_PAIR(word, ae, ao)                                        \
    do {                                                              \
        H2U _p; _p.u = (word);                                        \
        (ae) = __builtin_amdgcn_fdot2(_p.h, selE.h, (ae), false);     \
        (ao) = __builtin_amdgcn_fdot2(_p.h, selO.h, (ao), false);     \
    } while (0)

// ---- single-generation static-pinned, edge-parallel slab aggregation ------
// Grid = 2048 co-resident blocks. cg = bid&3 (matches XCD = bid%8 since
// bid===x mod 8 => bid===x mod 4); rank = bid>>2 grid-strides over 64-node
// buckets. No atomics, no queue, no later generations -> pinning fixed at t=0.
// LDS fp32 acc[64][17]; 64 slots x 4 lanes (uint2 = 8 B of the 32 B slab row);
// contiguous dst-sorted chunk per slot; register run accumulation with LDS
// atomic flush at run boundaries; pack prefetch d4, row prefetch d2.
// MODE 0: relu(acc+bias); MODE 1: plain.
#define QBKT 64
#define QST 17

template <int MODE>
__global__ __launch_bounds__(256) void agg_s_kernel(
        const _Float16* __restrict__ t, const int* __restrict__ offs,
        const int* __restrict__ esrc, const float* __restrict__ bias,
        _Float16* __restrict__ out, int N, int nBkt) {
    __shared__ float acc[QBKT * QST];
    int tid = threadIdx.x;  // 256
    int cg = blockIdx.x & 3;
    int rank = blockIdx.x >> 2;
    int stride = gridDim.x >> 2;
    const uint2* slab = (const uint2*)(t + (size_t)cg * N * 16);

    H2U selE, selO;
    selE.h = half2h{(_Float16)1.f, (_Float16)0.f};
    selO.h = half2h{(_Float16)0.f, (_Float16)1.f};

    for (int b = rank; b < nBkt; b += stride) {
        for (int i = tid; i < QBKT * QST; i += 256) acc[i] = 0.f;
        __syncthreads();
        int g0 = b << 6;
        int g1 = min(g0 + QBKT, N);
        int beg = offs[g0], end = offs[g1];

        int nE = end - beg;
        int chunk = (nE + 63) >> 6;              // 64 slots
        int slot = tid >> 2;
        int c = tid & 3;                         // 4 lanes x uint2
        int e0 = beg + slot * chunk;
        int e1 = min(e0 + chunk, end);

        if (e0 < e1) {
            float a0 = 0.f, a1 = 0.f, a2 = 0.f, a3 = 0.f;
            int p0 = esrc[e0];
            int p1 = esrc[e0 + 1];
            int p2 = esrc[e0 + 2];
            int p3 = esrc[e0 + 3];
            uint2 v0 = slab[(size_t)(p0 & 0x1FFFF) * 4 + c];
            uint2 v1 = slab[(size_t)(p1 & 0x1FFFF) * 4 + c];
            int cur = (p0 >> 17) & 63;
            for (int e = e0; e < e1; ++e) {
                uint2 v2 = slab[(size_t)(p2 & 0x1FFFF) * 4 + c];   // row e+2
                int p4 = esrc[e + 4];                              // pack e+4
                int dl = (p0 >> 17) & 63;
                if (dl != cur) {                 // run boundary: flush
                    float* fp = &acc[cur * QST + c * 4];
                    atomicAdd(&fp[0], a0); atomicAdd(&fp[1], a1);
                    atomicAdd(&fp[2], a2); atomicAdd(&fp[3], a3);
                    a0 = a1 = a2 = a3 = 0.f;
                    cur = dl;
                }
                ACC_PAIR(v0.x, a0, a1);
                ACC_PAIR(v0.y, a2, a3);
                p0 = p1; p1 = p2; p2 = p3; p3 = p4;
                v0 = v1; v1 = v2;
            }
            float* fp = &acc[cur * QST + c * 4];
            atomicAdd(&fp[0], a0); atomicAdd(&fp[1], a1);
            atomicAdd(&fp[2], a2); atomicAdd(&fp[3], a3);
        }
        __syncthreads();

        // epilogue: 256 threads = 64 nodes x 4 col-quads; 8 B stores
        {
            int node = tid >> 2, cq = tid & 3;
            int gn = g0 + node;
            if (gn < N) {
                const float* ap = &acc[node * QST + cq * 4];
                half4h hv;
#pragma unroll
                for (int k = 0; k < 4; ++k) {
                    float v = ap[k];
                    if (MODE == 0) v = fmaxf(v + bias[cg * 16 + cq * 4 + k], 0.f);
                    hv[k] = (_Float16)v;
                }
                *(half4h*)(out + ((size_t)cg * N + gn) * 16 + cq * 4) = hv;
            }
        }
        __syncthreads();   // acc reused next bucket
    }
}

// ---------------- loss ----------------
__global__ void loss_pass(const float* __restrict__ rep, const int* __restrict__ labels, int N,
                          double* __restrict__ colSum, double* __restrict__ pickedSum,
                          int* __restrict__ cnt) {
    const int G = 8;
    const int ROWS = 512;
    int t = threadIdx.x;  // blockDim = 320
    int c = t % NCLS;
    int g = t / NCLS;
    int base = blockIdx.x * ROWS;
    int lim = min(base + ROWS, N);
    double sumLoc = 0.0, pickLoc = 0.0;
    int cntLoc = 0;
    for (int r = base + g; r < lim; r += G) {
        float v = rep[(size_t)r * NCLS + c];
        sumLoc += exp((double)v);
        if (labels[r] == c) { pickLoc += (double)v; cntLoc++; }
    }
    __shared__ double colP[G][NCLS];
    __shared__ int cntP[G][NCLS];
    __shared__ double waveP[5];
    colP[g][c] = sumLoc;
    cntP[g][c] = cntLoc;
    __syncthreads();
    if (g == 0) {
        double tot = 0.0;
        int ctot = 0;
        for (int gg = 0; gg < G; ++gg) { tot += colP[gg][c]; ctot += cntP[gg][c]; }
        atomicAdd(&colSum[c], tot);
        if (ctot) atomicAdd(&cnt[c], ctot);
    }
    double wv = pickLoc;
    for (int off = 32; off; off >>= 1) wv += __shfl_down(wv, off, 64);
    if ((t & 63) == 0) waveP[t >> 6] = wv;
    __syncthreads();
    if (t == 0) {
        double s = 0.0;
        for (int i = 0; i < 5; ++i) s += waveP[i];
        atomicAdd(pickedSum, s);
    }
}

__global__ void finalize_kernel(const double* __restrict__ colSum, const int* __restrict__ cnt,
                                const double* __restrict__ pickedSum, int N,
                                float* __restrict__ lossOut) {
    int t = threadIdx.x;
    double term = 0.0;
    if (t < NCLS) term = (double)cnt[t] * log(colSum[t]);
    for (int off = 32; off; off >>= 1) term += __shfl_down(term, off, 64);
    if (t == 0) lossOut[0] = (float)((term - pickedSum[0]) / (double)N);
}

extern "C" void kernel_launch(void* const* d_in, const int* in_sizes, int n_in,
                              void* d_out, int out_size, void* d_ws, size_t ws_size,
                              hipStream_t stream) {
    const float* features = (const float*)d_in[0];
    const float* W0 = (const float*)d_in[1];
    const float* b0 = (const float*)d_in[2];
    const float* W1 = (const float*)d_in[3];
    const float* b1 = (const float*)d_in[4];
    const float* W2 = (const float*)d_in[5];
    const float* b2 = (const float*)d_in[6];
    const int* src = (const int*)d_in[7];
    const int* dst = (const int*)d_in[8];
    const int* labels = (const int*)d_in[9];

    const int N = in_sizes[0] / 64;
    const int E = in_sizes[7];
    const int NC = in_sizes[6];  // 40

    char* ws = (char*)d_ws;
    size_t off = 0;
    auto alloc = [&](size_t bytes) -> void* {
        void* p = ws + off;
        off = (off + bytes + 255) & ~(size_t)255;
        return p;
    };
    int* offs      = (int*)alloc((size_t)(N + 1) * 4);
    int* esrc      = (int*)alloc((size_t)(E + 8) * 4);  // +8: pipeline pad
    _Float16* bufA = (_Float16*)alloc((size_t)N * 64 * 2);  // sliced [4][N][16]
    _Float16* bufB = (_Float16*)alloc((size_t)N * 64 * 2);  // sliced [4][N][16]
    unsigned* tmp  = (unsigned*)alloc((size_t)E * 4);
    int* blockHist = (int*)alloc((size_t)MAXB1 * MAXNB * 4);
    int* blockBase = (int*)alloc((size_t)MAXB1 * MAXNB * 4);
    int* bucketOffs= (int*)alloc((size_t)(MAXNB + 1) * 4);
    char* red      = (char*)alloc(512);
    double* colSum    = (double*)red;
    double* pickedSum = (double*)(red + 320);
    int* cntRed       = (int*)(red + 328);

    float* rep = (float*)d_out;
    float* lossOut = rep + (size_t)N * NC;

    const int nb  = (N + 1023) >> 10;
    const int nB1 = (E + EPB - 1) / EPB;

    // fused: edge histogram + gemm0 (t0 = fp16(X@W0), sliced) in one dispatch
    hist_and_gemm<<<nB1 + 2048, 256, 0, stream>>>(dst, E, nb, blockHist, nB1,
                                                  features, W0, bufA, N);
    bucket_scan<<<1, 128, 0, stream>>>(blockHist, nB1, nb, blockBase, bucketOffs, offs, N, E,
                                       (int*)red, esrc);
    bucket_place<<<nB1, 256, 0, stream>>>(src, dst, E, nb, blockBase, tmp);
    bucket_finalize<<<nb, 512, 0, stream>>>(tmp, bucketOffs, N, offs, esrc);

    const int nBkt = (N + QBKT - 1) >> 6;
    const int AGG_GRID = 2048;   // 8 blocks/CU, fully co-resident: 1 generation

    // layer 0: h1 = fp16(relu(S@t0 + b0))   [sliced]
    agg_s_kernel<0><<<AGG_GRID, 256, 0, stream>>>(bufA, offs, esrc, b0, bufB, N, nBkt);
    // layer 1: t1 = fp16(h1@W1) ; h2 = fp16(relu(S@t1 + b1))   [sliced]
    gemm_fdot<<<2048, 256, 0, stream>>>(bufB, 1, W1, nullptr, bufA, 1, N, 64);
    agg_s_kernel<0><<<AGG_GRID, 256, 0, stream>>>(bufA, offs, esrc, b1, bufB, N, nBkt);
    // layer 2 (agg-first): g2 = fp16(S@h2) [sliced] ; rep = g2@W2 + b2 [fp32]
    agg_s_kernel<1><<<AGG_GRID, 256, 0, stream>>>(bufB, offs, esrc, nullptr, bufA, N, nBkt);
    gemm_fdot<<<2048, 256, 0, stream>>>(bufA, 1, W2, b2, rep, 0, N, NC);

    // loss
    loss_pass<<<(N + 511) / 512, 320, 0, stream>>>(rep, labels, N, colSum, pickedSum, cntRed);
    finalize_kernel<<<1, 64, 0, stream>>>(colSum, cntRed, pickedSum, N, lossOut);
}

// Round 7
// 389.530 us; speedup vs baseline: 2.1197x; 1.2397x over previous
//
#include <hip/hip_runtime.h>
#include <hip/hip_bf16.h>
#include <hip/hip_fp16.h>

#define NCLS 40

typedef __attribute__((ext_vector_type(8))) _Float16 half8;
typedef __attribute__((ext_vector_type(2))) _Float16 half2h;
union H2U { half2h h; unsigned u; };

// Layout decision (rounds 0-6 post-mortem): gathers are line-request x latency
// bound (MSHR-capped). 128-B fp16 rows [N][64] are line-optimal (1.7M
// line-requests/agg); any column slicing multiplies requests 4x and loses
// (round 6: 83us vs 44us). So buffers stay UNSLICED; the remaining lever is
// issue cost per gather -> agg_d_kernel: 8 nodes/wave, 8 lanes/node,
// register-only accumulation, no shuffles/LDS/atomics.

// ---------------- CSR build: bucketed counting sort ----------------
#define EPB 16384     // edges per level-1 block
#define MAXB1 128     // max level-1 blocks (E <= MAXB1*EPB)
#define MAXNB 104     // max buckets (N <= MAXNB*1024)

// Fused: blocks [0,nB1) do the edge histogram; blocks [nB1,..) do gemm0
// (X fp32 [N,64] @ W0 -> fp16 out). Independent work, complementary pipes.
__global__ __launch_bounds__(256) void hist_and_gemm(
        const int* __restrict__ dst, int E, int nb, int* __restrict__ blockHist, int nB1,
        const float* __restrict__ X, const float* __restrict__ W,
        _Float16* __restrict__ out, int N) {
    __shared__ int cnt[4][MAXNB];
    int t = threadIdx.x;  // 256
    if ((int)blockIdx.x < nB1) {
        for (int i = t; i < 4 * MAXNB; i += 256) cnt[i / MAXNB][i % MAXNB] = 0;
        __syncthreads();
        int bk = t & 3;
        int base = blockIdx.x * EPB;
        int end = min(base + EPB, E);
        for (int i = base + t; i < end; i += 256) atomicAdd(&cnt[bk][dst[i] >> 10], 1);
        __syncthreads();
        for (int i = t; i < nb; i += 256)
            blockHist[blockIdx.x * nb + i] = cnt[0][i] + cnt[1][i] + cnt[2][i] + cnt[3][i];
        return;
    }
    // ---- gemm0 part ----
    int bid = blockIdx.x - nB1;
    int nBlocks = gridDim.x - nB1;
    int lane = t & 63;
    int waveId = (bid * 256 + t) >> 6;
    int nWaves = (nBlocks * 256) >> 6;
    int p = lane & 31;

    H2U wh[32];
#pragma unroll
    for (int j = 0; j < 32; ++j)
        wh[j].h = half2h{(_Float16)W[(2 * j) * 64 + lane], (_Float16)W[(2 * j + 1) * 64 + lane]};

    const float2* Xf = (const float2*)X;
    auto loadX = [&](int row) -> H2U {
        H2U r; r.u = 0;
        if (row < N) {
            float2 f = Xf[(size_t)row * 32 + p];
            r.h = half2h{(_Float16)f.x, (_Float16)f.y};
        }
        return r;
    };
    int row = waveId;
    H2U xp = loadX(row);
    for (; row < N; row += nWaves) {
        H2U nxt = loadX(row + nWaves);
        float y0 = 0.f, y1 = 0.f;
#pragma unroll
        for (int j2 = 0; j2 < 32; j2 += 2) {
            H2U r0, r1;
            r0.u = __builtin_amdgcn_readlane(xp.u, j2);
            r1.u = __builtin_amdgcn_readlane(xp.u, j2 + 1);
            y0 = __builtin_amdgcn_fdot2(r0.h, wh[j2].h, y0, false);
            y1 = __builtin_amdgcn_fdot2(r1.h, wh[j2 + 1].h, y1, false);
        }
        out[(size_t)row * 64 + lane] = (_Float16)(y0 + y1);
        xp = nxt;
    }
}

// also zeroes the 512-byte reduction scratch, writes the esrc prefetch pad
__global__ void bucket_scan(const int* __restrict__ blockHist, int nB1, int nb,
                            int* __restrict__ blockBase, int* __restrict__ bucketOffs,
                            int* __restrict__ offs, int N, int E, int* __restrict__ red32,
                            int* __restrict__ esrc) {
    __shared__ int h[MAXB1 * MAXNB];
    __shared__ int btot[MAXNB];
    __shared__ int boffs[MAXNB + 1];
    int t = threadIdx.x;  // 128
    if (t < 128) red32[t] = 0;
    int total = nB1 * nb;
    for (int i = t; i < total; i += 128) h[i] = blockHist[i];
    __syncthreads();
    for (int b = t; b < nb; b += 128) {
        int run = 0;
        for (int i = 0; i < nB1; ++i) { int v = h[i * nb + b]; h[i * nb + b] = run; run += v; }
        btot[b] = run;
    }
    __syncthreads();
    if (t == 0) {
        int run = 0;
        for (int b = 0; b < nb; ++b) { boffs[b] = run; run += btot[b]; }
        boffs[nb] = run;
    }
    __syncthreads();
    for (int b = t; b < nb; b += 128) {
        int bo = boffs[b];
        for (int i = 0; i < nB1; ++i) h[i * nb + b] += bo;
    }
    __syncthreads();
    for (int i = t; i < total; i += 128) blockBase[i] = h[i];
    for (int b = t; b <= nb; b += 128) bucketOffs[b] = boffs[b];
    if (t == 0) { offs[N] = E; }
    if (t < 8) esrc[E + t] = 0;   // safety pad
}

__global__ void bucket_place(const int* __restrict__ src, const int* __restrict__ dst, int E,
                             int nb, const int* __restrict__ blockBase,
                             unsigned* __restrict__ tmp) {
    __shared__ int cur[MAXNB];
    int t = threadIdx.x;  // 256
    for (int i = t; i < nb; i += 256) cur[i] = blockBase[blockIdx.x * nb + i];
    __syncthreads();
    int base = blockIdx.x * EPB;
    int end = min(base + EPB, E);
    for (int i = base + t; i < end; i += 256) {
        int d = dst[i];
        int s = src[i];
        unsigned pack = ((unsigned)(d & 1023) << 17) | (unsigned)s;  // src < 2^17
        int pos = atomicAdd(&cur[d >> 10], 1);
        tmp[pos] = pack;
    }
}

// esrc entry: bits [26:17] = dst mod 1024 (unused by agg; masked on read),
// bits [16:0] = src.
__global__ __launch_bounds__(512) void bucket_finalize(const unsigned* __restrict__ tmp,
                                                       const int* __restrict__ bucketOffs,
                                                       int N, int* __restrict__ offs,
                                                       int* __restrict__ esrc) {
    __shared__ int cnt[1024];
    __shared__ int wsum[8];
    int b = blockIdx.x;
    int t = threadIdx.x;  // 512
    int bstart = bucketOffs[b], bend = bucketOffs[b + 1];
    cnt[t] = 0;
    cnt[t + 512] = 0;
    __syncthreads();
    for (int i = bstart + t; i < bend; i += 512) atomicAdd(&cnt[tmp[i] >> 17], 1);
    __syncthreads();
    int c0 = cnt[2 * t], c1 = cnt[2 * t + 1];
    int s = c0 + c1;
    int lane = t & 63, w = t >> 6;
    int ssc = s;
    for (int off = 1; off < 64; off <<= 1) {
        int v = __shfl_up(ssc, off, 64);
        if (lane >= off) ssc += v;
    }
    if (lane == 63) wsum[w] = ssc;
    __syncthreads();
    int wo = 0;
#pragma unroll
    for (int k = 0; k < 8; ++k)
        if (k < w) wo += wsum[k];
    int excl = (ssc - s) + wo + bstart;
    __syncthreads();
    int node0 = (b << 10) + 2 * t;
    if (node0 < N) offs[node0] = excl;
    if (node0 + 1 < N) offs[node0 + 1] = excl + c0;
    cnt[2 * t] = excl;
    cnt[2 * t + 1] = excl + c0;
    __syncthreads();
    for (int i = bstart + t; i < bend; i += 512) {
        unsigned p = tmp[i];
        int pos = atomicAdd(&cnt[p >> 17], 1);
        esrc[pos] = (int)(p);
    }
}

// ------------- dense X[N,64] (fp16 or fp32) @ W[64,FO] ---------------------
__global__ __launch_bounds__(256) void gemm_fdot(const void* __restrict__ X, int xHalf,
                                                 const float* __restrict__ W,
                                                 const float* __restrict__ bias,
                                                 void* __restrict__ out, int outHalf,
                                                 int N, int FO) {
    int lane = threadIdx.x & 63;
    int waveId = (blockIdx.x * blockDim.x + threadIdx.x) >> 6;
    int nWaves = (gridDim.x * blockDim.x) >> 6;
    int cl = lane < FO ? lane : 0;
    int p = lane & 31;

    H2U wh[32];
#pragma unroll
    for (int j = 0; j < 32; ++j)
        wh[j].h = half2h{(_Float16)W[(2 * j) * FO + cl], (_Float16)W[(2 * j + 1) * FO + cl]};
    float gb = 0.f;
    if (bias != nullptr && lane < FO) gb = bias[lane];

    const unsigned* Xh = (const unsigned*)X;
    const float2* Xf = (const float2*)X;
    float* outF = (float*)out;
    _Float16* outH = (_Float16*)out;

    auto loadX = [&](int row) -> H2U {
        H2U r; r.u = 0;
        if (row < N) {
            if (xHalf) r.u = Xh[(size_t)row * 32 + p];
            else {
                float2 f = Xf[(size_t)row * 32 + p];
                r.h = half2h{(_Float16)f.x, (_Float16)f.y};
            }
        }
        return r;
    };

    int row = waveId;
    H2U xp = loadX(row);
    for (; row < N; row += nWaves) {
        H2U nxt = loadX(row + nWaves);
        float y0 = gb, y1 = 0.f;
#pragma unroll
        for (int j2 = 0; j2 < 32; j2 += 2) {
            H2U r0, r1;
            r0.u = __builtin_amdgcn_readlane(xp.u, j2);
            r1.u = __builtin_amdgcn_readlane(xp.u, j2 + 1);
            y0 = __builtin_amdgcn_fdot2(r0.h, wh[j2].h, y0, false);
            y1 = __builtin_amdgcn_fdot2(r1.h, wh[j2 + 1].h, y1, false);
        }
        float y = y0 + y1;
        if (lane < FO) {
            if (outHalf) outH[(size_t)row * FO + lane] = (_Float16)y;
            else         outF[(size_t)row * FO + lane] = y;
        }
        xp = nxt;
    }
}

// fdot2-selector accumulate: a_even += v.lo, a_odd += v.hi (exact: x*1.0, fp32 acc)
#define ACC_PAIR(word, ae, ao)                                        \
    do {                                                              \
        H2U _p; _p.u = (word);                                        \
        (ae) = __builtin_amdgcn_fdot2(_p.h, selE.h, (ae), false);     \
        (ao) = __builtin_amdgcn_fdot2(_p.h, selO.h, (ao), false);     \
    } while (0)

// ---------- direct-register aggregation: 8 nodes/wave, 8 lanes/node --------
// Each 8-lane slot owns one node: lane li holds cols [8li, 8li+8) in 8 fp32
// regs; per edge one uint4 (16 B) load = full 128-B row across the slot
// (line-optimal). Depth-2 row pipeline + depth-3 esrc pipeline (clamped
// indices, no OOB). No LDS, no shuffles, no atomics, no barriers.
// MODE 0: out = fp16(relu(acc + bias)); MODE 1: out = fp16(acc).
template <int MODE>
__global__ __launch_bounds__(256) void agg_d_kernel(
        const _Float16* __restrict__ t, const int* __restrict__ offs,
        const int* __restrict__ esrc, const float* __restrict__ bias,
        _Float16* __restrict__ out, int N) {
    int tid = threadIdx.x;  // 256 -> 32 nodes per block
    int node = blockIdx.x * 32 + (tid >> 3);
    if (node >= N) return;
    int li = tid & 7;

    H2U selE, selO;
    selE.h = half2h{(_Float16)1.f, (_Float16)0.f};
    selO.h = half2h{(_Float16)0.f, (_Float16)1.f};

    int beg = offs[node], end = offs[node + 1];   // degree >= 1 (self-loops)
    const uint4* rows = (const uint4*)t;          // [N][8] uint4

    float a0 = 0.f, a1 = 0.f, a2 = 0.f, a3 = 0.f;
    float a4 = 0.f, a5 = 0.f, a6 = 0.f, a7 = 0.f;

    int j = beg;
    int cA = (j + 1 < end) ? j + 1 : beg;
    int cB = (j + 2 < end) ? j + 2 : beg;
    int s0 = esrc[j] & 0x1FFFF;
    int s1 = esrc[cA] & 0x1FFFF;
    int s2 = esrc[cB] & 0x1FFFF;
    uint4 v0 = rows[(size_t)s0 * 8 + li];
    uint4 v1 = rows[(size_t)s1 * 8 + li];
    for (; j < end; ++j) {
        int cC = (j + 3 < end) ? j + 3 : beg;
        int s3 = esrc[cC] & 0x1FFFF;
        uint4 v2 = rows[(size_t)s2 * 8 + li];     // row for edge j+2
        ACC_PAIR(v0.x, a0, a1);
        ACC_PAIR(v0.y, a2, a3);
        ACC_PAIR(v0.z, a4, a5);
        ACC_PAIR(v0.w, a6, a7);
        v0 = v1; v1 = v2; s2 = s3;
    }

    half8 hv;
    if (MODE == 0) {
        const float* bp = bias + li * 8;
        hv[0] = (_Float16)fmaxf(a0 + bp[0], 0.f);
        hv[1] = (_Float16)fmaxf(a1 + bp[1], 0.f);
        hv[2] = (_Float16)fmaxf(a2 + bp[2], 0.f);
        hv[3] = (_Float16)fmaxf(a3 + bp[3], 0.f);
        hv[4] = (_Float16)fmaxf(a4 + bp[4], 0.f);
        hv[5] = (_Float16)fmaxf(a5 + bp[5], 0.f);
        hv[6] = (_Float16)fmaxf(a6 + bp[6], 0.f);
        hv[7] = (_Float16)fmaxf(a7 + bp[7], 0.f);
    } else {
        hv[0] = (_Float16)a0; hv[1] = (_Float16)a1;
        hv[2] = (_Float16)a2; hv[3] = (_Float16)a3;
        hv[4] = (_Float16)a4; hv[5] = (_Float16)a5;
        hv[6] = (_Float16)a6; hv[7] = (_Float16)a7;
    }
    *(half8*)(out + (size_t)node * 64 + li * 8) = hv;
}

// ---------------- loss ----------------
__global__ void loss_pass(const float* __restrict__ rep, const int* __restrict__ labels, int N,
                          double* __restrict__ colSum, double* __restrict__ pickedSum,
                          int* __restrict__ cnt) {
    const int G = 8;
    const int ROWS = 512;
    int t = threadIdx.x;  // blockDim = 320
    int c = t % NCLS;
    int g = t / NCLS;
    int base = blockIdx.x * ROWS;
    int lim = min(base + ROWS, N);
    double sumLoc = 0.0, pickLoc = 0.0;
    int cntLoc = 0;
    for (int r = base + g; r < lim; r += G) {
        float v = rep[(size_t)r * NCLS + c];
        sumLoc += exp((double)v);
        if (labels[r] == c) { pickLoc += (double)v; cntLoc++; }
    }
    __shared__ double colP[G][NCLS];
    __shared__ int cntP[G][NCLS];
    __shared__ double waveP[5];
    colP[g][c] = sumLoc;
    cntP[g][c] = cntLoc;
    __syncthreads();
    if (g == 0) {
        double tot = 0.0;
        int ctot = 0;
        for (int gg = 0; gg < G; ++gg) { tot += colP[gg][c]; ctot += cntP[gg][c]; }
        atomicAdd(&colSum[c], tot);
        if (ctot) atomicAdd(&cnt[c], ctot);
    }
    double wv = pickLoc;
    for (int off = 32; off; off >>= 1) wv += __shfl_down(wv, off, 64);
    if ((t & 63) == 0) waveP[t >> 6] = wv;
    __syncthreads();
    if (t == 0) {
        double s = 0.0;
        for (int i = 0; i < 5; ++i) s += waveP[i];
        atomicAdd(pickedSum, s);
    }
}

__global__ void finalize_kernel(const double* __restrict__ colSum, const int* __restrict__ cnt,
                                const double* __restrict__ pickedSum, int N,
                                float* __restrict__ lossOut) {
    int t = threadIdx.x;
    double term = 0.0;
    if (t < NCLS) term = (double)cnt[t] * log(colSum[t]);
    for (int off = 32; off; off >>= 1) term += __shfl_down(term, off, 64);
    if (t == 0) lossOut[0] = (float)((term - pickedSum[0]) / (double)N);
}

extern "C" void kernel_launch(void* const* d_in, const int* in_sizes, int n_in,
                              void* d_out, int out_size, void* d_ws, size_t ws_size,
                              hipStream_t stream) {
    const float* features = (const float*)d_in[0];
    const float* W0 = (const float*)d_in[1];
    const float* b0 = (const float*)d_in[2];
    const float* W1 = (const float*)d_in[3];
    const float* b1 = (const float*)d_in[4];
    const float* W2 = (const float*)d_in[5];
    const float* b2 = (const float*)d_in[6];
    const int* src = (const int*)d_in[7];
    const int* dst = (const int*)d_in[8];
    const int* labels = (const int*)d_in[9];

    const int N = in_sizes[0] / 64;
    const int E = in_sizes[7];
    const int NC = in_sizes[6];  // 40

    char* ws = (char*)d_ws;
    size_t off = 0;
    auto alloc = [&](size_t bytes) -> void* {
        void* p = ws + off;
        off = (off + bytes + 255) & ~(size_t)255;
        return p;
    };
    int* offs      = (int*)alloc((size_t)(N + 1) * 4);
    int* esrc      = (int*)alloc((size_t)(E + 8) * 4);  // +8: safety pad
    _Float16* bufA = (_Float16*)alloc((size_t)N * 64 * 2);  // unsliced [N][64]
    _Float16* bufB = (_Float16*)alloc((size_t)N * 64 * 2);  // unsliced [N][64]
    unsigned* tmp  = (unsigned*)alloc((size_t)E * 4);
    int* blockHist = (int*)alloc((size_t)MAXB1 * MAXNB * 4);
    int* blockBase = (int*)alloc((size_t)MAXB1 * MAXNB * 4);
    int* bucketOffs= (int*)alloc((size_t)(MAXNB + 1) * 4);
    char* red      = (char*)alloc(512);
    double* colSum    = (double*)red;
    double* pickedSum = (double*)(red + 320);
    int* cntRed       = (int*)(red + 328);

    float* rep = (float*)d_out;
    float* lossOut = rep + (size_t)N * NC;

    const int nb  = (N + 1023) >> 10;
    const int nB1 = (E + EPB - 1) / EPB;

    // fused: edge histogram + gemm0 (t0 = fp16(X@W0)) in one dispatch
    hist_and_gemm<<<nB1 + 2048, 256, 0, stream>>>(dst, E, nb, blockHist, nB1,
                                                  features, W0, bufA, N);
    bucket_scan<<<1, 128, 0, stream>>>(blockHist, nB1, nb, blockBase, bucketOffs, offs, N, E,
                                       (int*)red, esrc);
    bucket_place<<<nB1, 256, 0, stream>>>(src, dst, E, nb, blockBase, tmp);
    bucket_finalize<<<nb, 512, 0, stream>>>(tmp, bucketOffs, N, offs, esrc);

    const int aggGrid = (N + 31) / 32;   // 32 nodes per 256-thread block

    // layer 0: h1 = fp16(relu(S@t0 + b0))
    agg_d_kernel<0><<<aggGrid, 256, 0, stream>>>(bufA, offs, esrc, b0, bufB, N);
    // layer 1: t1 = fp16(h1@W1) ; h2 = fp16(relu(S@t1 + b1))
    gemm_fdot<<<2048, 256, 0, stream>>>(bufB, 1, W1, nullptr, bufA, 1, N, 64);
    agg_d_kernel<0><<<aggGrid, 256, 0, stream>>>(bufA, offs, esrc, b1, bufB, N);
    // layer 2 (agg-first, reference order): u = fp16(S@h2) ; rep = u@W2 + b2
    agg_d_kernel<1><<<aggGrid, 256, 0, stream>>>(bufB, offs, esrc, nullptr, bufA, N);
    gemm_fdot<<<2048, 256, 0, stream>>>(bufA, 1, W2, b2, rep, 0, N, NC);

    // loss
    loss_pass<<<(N + 511) / 512, 320, 0, stream>>>(rep, labels, N, colSum, pickedSum, cntRed);
    finalize_kernel<<<1, 64, 0, stream>>>(colSum, cntRed, pickedSum, N, lossOut);
}